// Round 9
// baseline (1429.701 us; speedup 1.0000x reference)
//
#include <hip/hip_runtime.h>

// Problem constants (from reference setup_inputs)
#define NVOX   4096   // B voxels
#define NMEAS  256    // M measurements
#define NATOMS 512    // K atoms
#define NITER  30

typedef __attribute__((ext_vector_type(8))) short s8v;   // 8 bf16 (4 VGPR) MFMA frag
typedef __attribute__((ext_vector_type(4))) short s4v;
typedef __attribute__((ext_vector_type(4))) float f32x4;

// bf16 round-to-nearest-even split helpers (no NaN/Inf in this problem)
__device__ __forceinline__ unsigned short f2bf(float x) {
    unsigned u = __builtin_bit_cast(unsigned, x);
    u += 0x7fff + ((u >> 16) & 1);
    return (unsigned short)(u >> 16);
}
__device__ __forceinline__ float bf2f(unsigned short b) {
    unsigned u = ((unsigned)b) << 16;
    return __builtin_bit_cast(float, u);
}
// g(v) = (z - u) collapsed through v = x + u :  relu(v-0.1) - min(v,0.1)
__device__ __forceinline__ float g_of(float v) {
    return fmaxf(v - 0.1f, 0.0f) - fminf(v, 0.1f);
}

// ---------------------------------------------------------------------------
// K0: G = I + A*A^T in fp64 (Gd) + fp32 copy (Gf) for the sweep
// ---------------------------------------------------------------------------
__global__ __launch_bounds__(256) void g_kernel_d(const float* __restrict__ A,
                                                  double* __restrict__ Gd,
                                                  float* __restrict__ Gf) {
    __shared__ float arow[NATOMS];
    int i = blockIdx.x;
    for (int k = threadIdx.x; k < NATOMS; k += 256) arow[k] = A[i * NATOMS + k];
    __syncthreads();
    int j = threadIdx.x;
    const float* aj = A + j * NATOMS;
    double s = (i == j) ? 1.0 : 0.0;
#pragma unroll 4
    for (int k = 0; k < NATOMS; ++k) s += (double)arow[k] * (double)aj[k];
    Gd[i * NMEAS + j] = s;
    Gf[i * NMEAS + j] = (float)s;
}

// ---------------------------------------------------------------------------
// K1: SPD inverse of Gf (256x256), BLOCKED symmetric SWEEP, panel NB=4.
// r8 lesson: launch_bounds 2nd arg does NOT lift the allocator's 128-reg
// occupancy heuristic — a 512-thr/vals[2][8][8] layout spills no matter what.
// Fix: 1024 threads so per-thread state FITS 128: vals[8][8]=64 + B 16 +
// E-half 16 + transients ~ 105 regs. amdgpu_waves_per_eu(4,4) pins the
// scheduler's occupancy target to the forced 4 waves/EU (16-wave block) so
// it doesn't squeeze toward 64 regs (r2's VGPR=56 hidden-spill signature).
// All register indexing compile-time (rule #20): guard-select on hf.
// Thread t: rb=t&31 owns rows 8rb+i; cb=t>>5 owns cols 8cb+j.
// sweep(all pivots) = -G^{-1}; negate on store. Algebra == r7/r8 (PASSED).
// ---------------------------------------------------------------------------
__global__ __launch_bounds__(1024) __attribute__((amdgpu_waves_per_eu(4, 4)))
void sweep_blk1024(const float* __restrict__ src, float* __restrict__ dst) {
    __shared__ float U[4][8][32];   // [col-slot a][row-in-block i][rb] : 4 KB
    int t = threadIdx.x;
    int rb = t & 31;
    int cb = t >> 5;                // [0,32)
    float vals[8][8];
#pragma unroll
    for (int i = 0; i < 8; ++i) {
        const float* row = &src[(8 * rb + i) * NMEAS + 8 * cb];
        float4 a = *(const float4*)row;
        float4 b = *(const float4*)(row + 4);
        vals[i][0] = a.x; vals[i][1] = a.y; vals[i][2] = a.z; vals[i][3] = a.w;
        vals[i][4] = b.x; vals[i][5] = b.y; vals[i][6] = b.z; vals[i][7] = b.w;
    }

#pragma unroll 1
    for (int s = 0; s < 64; ++s) {
        int pcb  = s >> 1;          // pivot col-block [0,32)
        int hsel = s & 1;           // which half (ph = hsel*4)
        __syncthreads();            // protect U from previous step's readers
        if (cb == pcb) {            // publish pivot panel: U[a][i][rb]
#pragma unroll
            for (int hf = 0; hf < 2; ++hf) {
                if (hf != hsel) continue;            // uniform cond, hf literal
#pragma unroll
                for (int a = 0; a < 4; ++a)
#pragma unroll
                    for (int i = 0; i < 8; ++i)
                        U[a][i][rb] = vals[i][hf * 4 + a];
            }
        }
        __syncthreads();

        int ph = hsel * 4;          // runtime ph: ONLY used in LDS addressing
        // ---- B = App^{-1} via in-register 4x4 sweep (redundant per thread)
        float P[4][4];
#pragma unroll
        for (int a = 0; a < 4; ++a)
#pragma unroll
            for (int b = 0; b < 4; ++b)
                P[a][b] = U[b][ph + a][pcb];         // LDS read, uniform addr
#pragma unroll
        for (int p = 0; p < 4; ++p) {
            float inv = 1.0f / P[p][p];
            float rv[4], cv[4];
#pragma unroll
            for (int a = 0; a < 4; ++a) rv[a] = P[a][p];
#pragma unroll
            for (int b = 0; b < 4; ++b) cv[b] = P[p][b] * inv;
#pragma unroll
            for (int a = 0; a < 4; ++a)
#pragma unroll
                for (int b = 0; b < 4; ++b) P[a][b] -= rv[a] * cv[b];
#pragma unroll
            for (int b = 0; b < 4; ++b) P[p][b] = cv[b];
#pragma unroll
            for (int a = 0; a < 4; ++a) P[a][p] = rv[a] * inv;
            P[p][p] = -inv;
        }
        float B[4][4];              // P holds -App^{-1}
#pragma unroll
        for (int a = 0; a < 4; ++a)
#pragma unroll
            for (int b = 0; b < 4; ++b) B[a][b] = -P[a][b];

        // ---- update in two j-halves (E-half = 16 regs caps peak pressure)
#pragma unroll
        for (int jh = 0; jh < 2; ++jh) {
            float E4[4][4];         // E4[jj][a] = sum_b B[a][b]*N_{jh*4+jj}[b]
#pragma unroll
            for (int jj = 0; jj < 4; ++jj) {
                float n0 = U[0][jh * 4 + jj][cb], n1 = U[1][jh * 4 + jj][cb],
                      n2 = U[2][jh * 4 + jj][cb], n3 = U[3][jh * 4 + jj][cb];
#pragma unroll
                for (int a = 0; a < 4; ++a)
                    E4[jj][a] = B[a][0] * n0 + B[a][1] * n1
                              + B[a][2] * n2 + B[a][3] * n3;
            }
#pragma unroll
            for (int i = 0; i < 8; ++i) {
                float m0 = U[0][i][rb], m1 = U[1][i][rb],
                      m2 = U[2][i][rb], m3 = U[3][i][rb];
#pragma unroll
                for (int jj = 0; jj < 4; ++jj)
                    vals[i][jh * 4 + jj] -= m0 * E4[jj][0] + m1 * E4[jj][1]
                                          + m2 * E4[jj][2] + m3 * E4[jj][3];
            }
            if (rb == pcb) {        // pivot-row fixup: rows 4s..4s+3 -> E4
#pragma unroll
                for (int hf = 0; hf < 2; ++hf) {
                    if (hf != hsel) continue;
#pragma unroll
                    for (int ii = 0; ii < 4; ++ii)
#pragma unroll
                        for (int jj = 0; jj < 4; ++jj)
                            vals[hf * 4 + ii][jh * 4 + jj] = E4[jj][ii];
                }
            }
        }
        // ---- pivot-col fixup: cols 4s..4s+3 -> M_i . B[:,a]
        if (cb == pcb) {
#pragma unroll
            for (int hf = 0; hf < 2; ++hf) {
                if (hf != hsel) continue;
#pragma unroll
                for (int i = 0; i < 8; ++i) {
                    float m0 = U[0][i][rb], m1 = U[1][i][rb],
                          m2 = U[2][i][rb], m3 = U[3][i][rb];
#pragma unroll
                    for (int a = 0; a < 4; ++a)
                        vals[i][hf * 4 + a] = m0 * B[0][a] + m1 * B[1][a]
                                            + m2 * B[2][a] + m3 * B[3][a];
                }
            }
        }
        // ---- diagonal block: -App^{-1}  (must be last)
        if (rb == pcb && cb == pcb) {
#pragma unroll
            for (int hf = 0; hf < 2; ++hf) {
                if (hf != hsel) continue;
#pragma unroll
                for (int ii = 0; ii < 4; ++ii)
#pragma unroll
                    for (int a = 0; a < 4; ++a)
                        vals[hf * 4 + ii][hf * 4 + a] = -B[ii][a];
            }
        }
    }
    // sweep(all) == -G^{-1}  ->  negate on store
#pragma unroll
    for (int i = 0; i < 8; ++i)
#pragma unroll
        for (int j = 0; j < 8; ++j)
            dst[(8 * rb + i) * NMEAS + 8 * cb + j] = -vals[i][j];
}

// ---------------------------------------------------------------------------
// fp64 Newton refinement:  P = Gd @ X ;  Xn = 2X - X @ P   (X input fp32/fp64)
// (fp32 Newton was the r3/r4 bug: cancellation noise ~cond(G)*eps32)
// ---------------------------------------------------------------------------
template <typename TB>
__global__ __launch_bounds__(256) void mm_gd(const double* __restrict__ Gd,
                                             const TB* __restrict__ X,
                                             double* __restrict__ P) {
    __shared__ __align__(16) double row[NMEAS];
    int i = blockIdx.x;
    row[threadIdx.x] = Gd[i * NMEAS + threadIdx.x];
    __syncthreads();
    int j = threadIdx.x;
    double s = 0.0;
#pragma unroll 4
    for (int k = 0; k < NMEAS; ++k) s += row[k] * (double)X[k * NMEAS + j];
    P[i * NMEAS + j] = s;
}

template <typename TB>
__global__ __launch_bounds__(256) void upd_newton(const TB* __restrict__ X,
                                                  const double* __restrict__ P,
                                                  double* __restrict__ Xn) {
    __shared__ __align__(16) double row[NMEAS];
    int i = blockIdx.x;
    row[threadIdx.x] = (double)X[i * NMEAS + threadIdx.x];
    __syncthreads();
    int j = threadIdx.x;
    double s = 0.0;
#pragma unroll 4
    for (int k = 0; k < NMEAS; ++k) s += row[k] * P[k * NMEAS + j];
    Xn[i * NMEAS + j] = 2.0 * row[j] - s;
}

// ---------------------------------------------------------------------------
// K2: Hd = X2d @ A   (fp64 [256][256] @ fp32 [256][512] -> fp64 [256][512])
// ---------------------------------------------------------------------------
__global__ __launch_bounds__(256) void h_kernel_d(const double* __restrict__ Gi,
                                                  const float* __restrict__ A,
                                                  double* __restrict__ H) {
    __shared__ __align__(16) double grow[NMEAS];
    int i = blockIdx.x;
    grow[threadIdx.x] = Gi[i * NMEAS + threadIdx.x];
    __syncthreads();
    int k0 = threadIdx.x;
    double s0 = 0.0, s1 = 0.0;
#pragma unroll 4
    for (int j = 0; j < NMEAS; ++j) {
        double g = grow[j];
        s0 += g * (double)A[j * NATOMS + k0];
        s1 += g * (double)A[j * NATOMS + k0 + 256];
    }
    H[i * NATOMS + k0] = s0;
    H[i * NATOMS + k0 + 256] = s1;
}

// ---------------------------------------------------------------------------
// K3: W = I - A^T @ Hd  (fp64 accumulate), stored as bf16 hi/lo split
// ---------------------------------------------------------------------------
__global__ __launch_bounds__(256) void w_kernel_d(const float* __restrict__ A,
                                                  const double* __restrict__ H,
                                                  unsigned short* __restrict__ Whg,
                                                  unsigned short* __restrict__ Wlg) {
    __shared__ __align__(16) double acol[NMEAS];
    int p = blockIdx.x;
    acol[threadIdx.x] = (double)A[threadIdx.x * NATOMS + p];
    __syncthreads();
    int q0 = threadIdx.x;
    double s0 = 0.0, s1 = 0.0;
#pragma unroll 4
    for (int m = 0; m < NMEAS; ++m) {
        double a = acol[m];
        s0 += a * H[m * NATOMS + q0];
        s1 += a * H[m * NATOMS + q0 + 256];
    }
    double w0 = ((p == q0)       ? 1.0 : 0.0) - s0;
    double w1 = ((p == q0 + 256) ? 1.0 : 0.0) - s1;
    unsigned short h0 = f2bf((float)w0), h1 = f2bf((float)w1);
    Whg[p * NATOMS + q0]       = h0;
    Wlg[p * NATOMS + q0]       = f2bf((float)(w0 - (double)bf2f(h0)));
    Whg[p * NATOMS + q0 + 256] = h1;
    Wlg[p * NATOMS + q0 + 256] = f2bf((float)(w1 - (double)bf2f(h1)));
}

// ---------------------------------------------------------------------------
// K4: Delta0 = AtY (= t_1, since t_0 = 0), stored split bf16 hi/lo,
//     TRANSPOSED to [4096 voxels][512 atoms] for k-contiguous staging.
// AtY[k][b] = sum_m A[m][k] * Y[b][m]
// ---------------------------------------------------------------------------
__global__ __launch_bounds__(256) void aty_kernel(const float* __restrict__ A,
                                                  const float* __restrict__ Y,
                                                  unsigned short* __restrict__ Dh0,
                                                  unsigned short* __restrict__ Dl0) {
    __shared__ __align__(16) float At[64][65];
    __shared__ __align__(16) float Yt[64][65];
    int b0 = blockIdx.x * 64, k0 = blockIdx.y * 64;
    int t = threadIdx.x, tx = t & 15, ty = t >> 4;
    float acc[4][4] = {};
    for (int m0 = 0; m0 < NMEAS; m0 += 64) {
        __syncthreads();
        {
            int kk = t & 63, mr = t >> 6;
#pragma unroll
            for (int p = 0; p < 16; ++p)
                At[mr + 4 * p][kk] = A[(m0 + mr + 4 * p) * NATOMS + k0 + kk];
            int mm = t & 63, br = t >> 6;
#pragma unroll
            for (int p = 0; p < 16; ++p)
                Yt[mm][br + 4 * p] = Y[(b0 + br + 4 * p) * NMEAS + m0 + mm];
        }
        __syncthreads();
#pragma unroll 4
        for (int m = 0; m < 64; ++m) {
            float av[4], yv[4];
#pragma unroll
            for (int i = 0; i < 4; ++i) av[i] = At[m][ty * 4 + i];
#pragma unroll
            for (int j = 0; j < 4; ++j) yv[j] = Yt[m][tx * 4 + j];
#pragma unroll
            for (int i = 0; i < 4; ++i)
#pragma unroll
                for (int j = 0; j < 4; ++j) acc[i][j] += av[i] * yv[j];
        }
    }
#pragma unroll
    for (int j = 0; j < 4; ++j) {
        int b = b0 + tx * 4 + j;
        s4v h4, l4;
#pragma unroll
        for (int i = 0; i < 4; ++i) {
            float f = acc[i][j];
            unsigned short h = f2bf(f);
            h4[i] = (short)h;
            l4[i] = (short)f2bf(f - bf2f(h));
        }
        *(s4v*)&Dh0[(long)b * NATOMS + k0 + ty * 4] = h4;
        *(s4v*)&Dl0[(long)b * NATOMS + k0 + ty * 4] = l4;
    }
}

// ---------------------------------------------------------------------------
// K5: one ADMM iteration, DELTA form, bf16-split MFMA, 3 terms
//   (Wh*Dh + Wh*Dl + Wl*Dh; dropped Wl*Dl <= 2^-18 rel):
//   dx = W @ Delta_in ; x_k = x_{k-1}+dx ; v_k = x_k + min(v_{k-1},0.1)
//   Delta_out = g(v_k)-g(v_{k-1}) -> split bf16 transposed [n][k]
// LAST: out[b][k] = x_{k-1} + dx  (transposed fp32 write)
// r9 change: BN 128->64 (grid 512 = 2 blocks/CU, LDS 40KB) — r8 had 1
// block/CU = 1 wave/SIMD, so per-chunk HBM latency (~900cyc) was exposed
// behind only ~320cyc of MFMA. 2 independent blocks/CU interleave barriers.
// Per-C-element math/order identical to r5-proven kernel.
// Tile: BM=64 x BN=64, BK=32, 256 thr (4 waves), mfma_f32_16x16x32_bf16.
// ---------------------------------------------------------------------------
template <int FIRST, int LAST>
__global__ __launch_bounds__(256) void admm_delta(
        const unsigned short* __restrict__ Whg,
        const unsigned short* __restrict__ Wlg,
        const unsigned short* __restrict__ Dhg,
        const unsigned short* __restrict__ Dlg,
        float* __restrict__ xbuf,            // fp32 x [512][4096], in-place
        float* __restrict__ vbuf,            // fp32 v [512][4096], in-place (d_out)
        unsigned short* __restrict__ DhOut,
        unsigned short* __restrict__ DlOut,
        float* __restrict__ out) {
    __shared__ __align__(16) char smem[40960];
    unsigned short* Whs = (unsigned short*)smem;      // [2][64*40]
    unsigned short* Wls = Whs + 2 * 64 * 40;
    unsigned short* Dhs = Wls + 2 * 64 * 40;
    unsigned short* Dls = Dhs + 2 * 64 * 40;

    const int t = threadIdx.x;
    const int lane = t & 63, wv = t >> 6;
    const int ln = lane & 15, kg = lane >> 4;

    // XCD-aware bijective swizzle (grid 512 = 64x8, 8 XCDs, 64 blocks each):
    // XCD k gets bx in [8k,8k+8) x all by -> per-XCD L2: D 1MB + W 1MB.
    int bid = blockIdx.x + (blockIdx.y << 6);
    int xr = bid & 7, q = bid >> 3;
    int bx = xr * 8 + (q >> 3);          // [0,64)
    int by = q & 7;                      // [0,8)
    const int n0 = bx * 64, m0 = by * 64;

    const int wm = t >> 2, wslot = t & 3;     // staging: 64 rows x 4 slots
    const int tn = t >> 2, tslot = t & 3;

    f32x4 acc[4] = {};
    s8v rwh, rwl, rth, rtl;

#define GLOAD(kc)                                                             \
    {                                                                         \
        long ko = (long)(kc)*32;                                              \
        rwh = *(const s8v*)&Whg[(long)(m0 + wm) * NATOMS + ko + wslot * 8];   \
        rwl = *(const s8v*)&Wlg[(long)(m0 + wm) * NATOMS + ko + wslot * 8];   \
        rth = *(const s8v*)&Dhg[(long)(n0 + tn) * NATOMS + ko + tslot * 8];   \
        rtl = *(const s8v*)&Dlg[(long)(n0 + tn) * NATOMS + ko + tslot * 8];   \
    }
#define DSWRITE(b)                                                  \
    {                                                               \
        *(s8v*)&Whs[(b)*2560 + wm * 40 + wslot * 8] = rwh;          \
        *(s8v*)&Wls[(b)*2560 + wm * 40 + wslot * 8] = rwl;          \
        *(s8v*)&Dhs[(b)*2560 + tn * 40 + tslot * 8] = rth;          \
        *(s8v*)&Dls[(b)*2560 + tn * 40 + tslot * 8] = rtl;          \
    }

    GLOAD(0);
    DSWRITE(0);
#pragma unroll 1
    for (int c = 0; c < 16; ++c) {
        if (c < 15) GLOAD(c + 1);          // issue next chunk's loads early
        __syncthreads();                    // current buffer's ds_writes visible
        const int b = c & 1;
        const unsigned short* wh = &Whs[b * 2560];
        const unsigned short* wl = &Wls[b * 2560];
        const unsigned short* dh = &Dhs[b * 2560];
        const unsigned short* dl = &Dls[b * 2560];
        s8v ah[4], al[4], bh, bl;
#pragma unroll
        for (int mi = 0; mi < 4; ++mi) {
            ah[mi] = *(const s8v*)&wh[(mi * 16 + ln) * 40 + kg * 8];
            al[mi] = *(const s8v*)&wl[(mi * 16 + ln) * 40 + kg * 8];
        }
        {
            int r = wv * 16 + ln;
            bh = *(const s8v*)&dh[r * 40 + kg * 8];
            bl = *(const s8v*)&dl[r * 40 + kg * 8];
        }
#pragma unroll
        for (int mi = 0; mi < 4; ++mi) {
            acc[mi] = __builtin_amdgcn_mfma_f32_16x16x32_bf16(ah[mi], bh, acc[mi], 0, 0, 0);
            acc[mi] = __builtin_amdgcn_mfma_f32_16x16x32_bf16(ah[mi], bl, acc[mi], 0, 0, 0);
            acc[mi] = __builtin_amdgcn_mfma_f32_16x16x32_bf16(al[mi], bh, acc[mi], 0, 0, 0);
        }
        if (c < 15) DSWRITE((c + 1) & 1);  // prev use of that buffer done pre-barrier
    }
#undef GLOAD
#undef DSWRITE

    __syncthreads();                        // staging LDS dead; reuse as xT [64][68] f32
    float* xT = (float*)smem;

    if (!LAST) {
#pragma unroll
        for (int mi = 0; mi < 4; ++mi) {
            int nn = n0 + wv * 16 + ln;
            f32x4 dlt;
#pragma unroll
            for (int j = 0; j < 4; ++j) {
                int m = m0 + mi * 16 + kg * 4 + j;
                long idx = (long)m * NVOX + nn;
                float dx = acc[mi][j];
                float xn, vn, gold;
                if (FIRST) {
                    xn = dx; vn = xn; gold = 0.0f;   // x0=0, u0=0, v0=0
                } else {
                    xn = xbuf[idx] + dx;
                    float vp = vbuf[idx];
                    vn = xn + fminf(vp, 0.1f);
                    gold = g_of(vp);
                }
                xbuf[idx] = xn;
                vbuf[idx] = vn;
                dlt[j] = g_of(vn) - gold;
            }
            int nl = wv * 16 + ln;
            int ml = mi * 16 + kg * 4;
            *(f32x4*)&xT[nl * 68 + ml] = dlt;
        }
        __syncthreads();
        int nl = t >> 2, seg = t & 3;        // 64 rows x 16 m-cols per thread
#pragma unroll
        for (int q8 = 0; q8 < 2; ++q8) {
            s8v hv, lv;
#pragma unroll
            for (int e = 0; e < 8; ++e) {
                float f = xT[nl * 68 + seg * 16 + q8 * 8 + e];
                unsigned short h = f2bf(f);
                hv[e] = (short)h;
                lv[e] = (short)f2bf(f - bf2f(h));
            }
            *(s8v*)&DhOut[(long)(n0 + nl) * NATOMS + m0 + seg * 16 + q8 * 8] = hv;
            *(s8v*)&DlOut[(long)(n0 + nl) * NATOMS + m0 + seg * 16 + q8 * 8] = lv;
        }
    } else {
        // LAST: out[b][k] = x_{k-1}[k][b] + dx  (transposed fp32 write)
#pragma unroll
        for (int mi = 0; mi < 4; ++mi) {
            int nn = n0 + wv * 16 + ln;
            f32x4 tv;
#pragma unroll
            for (int j = 0; j < 4; ++j) {
                int m = m0 + mi * 16 + kg * 4 + j;
                tv[j] = xbuf[(long)m * NVOX + nn] + acc[mi][j];
            }
            int nl = wv * 16 + ln;
            int ml = mi * 16 + kg * 4;
            *(f32x4*)&xT[nl * 68 + ml] = tv;
        }
        __syncthreads();
        int nl = t >> 2, seg = t & 3;
#pragma unroll
        for (int q = 0; q < 4; ++q) {
            f32x4 v = *(const f32x4*)&xT[nl * 68 + seg * 16 + q * 4];
            *(f32x4*)&out[(long)(n0 + nl) * NATOMS + m0 + seg * 16 + q * 4] = v;
        }
    }
}

// ---------------------------------------------------------------------------
extern "C" void kernel_launch(void* const* d_in, const int* in_sizes, int n_in,
                              void* d_out, int out_size, void* d_ws, size_t ws_size,
                              hipStream_t stream) {
    const float* Y = (const float*)d_in[0];   // [4096][256]
    const float* A = (const float*)d_in[1];   // [256][512]

    // ws layout (float units), lifetime-checked overlays; total 6946816 floats
    // = 26.5 MiB (r3-r8 proven footprint).
    float* ws = (float*)d_ws;
    double* Gd  = (double*)(ws + 0);        // [0,131072)       dead after step 5
    float*  Gf  = ws + 131072;              // [131072,196608)  dead after sweep
    float*  X0f = ws + 196608;              // [196608,262144)  dead after step 4
    double* X1d = (double*)(ws + 262144);   // [262144,393216)  dead after step 6
    double* Pd  = (double*)(ws + 393216);   // [393216,524288)  dead after step 6
    double* X2d = (double*)(ws + 131072);   // overlays Gf+X0f (both dead)
    double* Hd  = (double*)(ws + 393216);   // [393216,655360) overlays Pd (dead)
    float*  xbuf = ws + 655360;             // [655360,2752512) fp32 x state
    unsigned short* Whg = (unsigned short*)(ws + 0);        // overlays Gd (dead)
    unsigned short* Wlg = (unsigned short*)(ws + 131072);   // overlays X2d (dead after h)
    unsigned short* DAh = (unsigned short*)(ws + 2752512);
    unsigned short* DAl = (unsigned short*)(ws + 3801088);
    unsigned short* DBh = (unsigned short*)(ws + 4849664);
    unsigned short* DBl = (unsigned short*)(ws + 5898240);  // end 6946816
    float* vbuf = (float*)d_out;   // v_k fp32, iters 1..29 (d_out as scratch)
    float* outp = (float*)d_out;   // final output, written by LAST iter only

    g_kernel_d<<<256, 256, 0, stream>>>(A, Gd, Gf);                 // 1
    sweep_blk1024<<<1, 1024, 0, stream>>>(Gf, X0f);                 // 2
    mm_gd<float><<<256, 256, 0, stream>>>(Gd, X0f, Pd);             // 3
    upd_newton<float><<<256, 256, 0, stream>>>(X0f, Pd, X1d);       // 4
    mm_gd<double><<<256, 256, 0, stream>>>(Gd, X1d, Pd);            // 5
    upd_newton<double><<<256, 256, 0, stream>>>(X1d, Pd, X2d);      // 6
    h_kernel_d<<<256, 256, 0, stream>>>(X2d, A, Hd);                // 7
    w_kernel_d<<<512, 256, 0, stream>>>(A, Hd, Whg, Wlg);           // 8
    aty_kernel<<<dim3(64, 8), 256, 0, stream>>>(A, Y, DAh, DAl);    // 9

    dim3 ig(NVOX / 64, NATOMS / 64);  // (64, 8) = 512 blocks = 2/CU
    unsigned short *ch = DAh, *cl = DAl, *nh = DBh, *nl = DBl;
    // iter 1: Delta_0 = AtY; x1 = W*AtY; v1 = x1; Delta_1 = g(v1)
    admm_delta<1, 0><<<ig, 256, 0, stream>>>(Whg, Wlg, ch, cl, xbuf, vbuf, nh, nl, nullptr);
    { unsigned short* s; s = ch; ch = nh; nh = s; s = cl; cl = nl; nl = s; }
    for (int it = 2; it <= NITER - 1; ++it) {
        admm_delta<0, 0><<<ig, 256, 0, stream>>>(Whg, Wlg, ch, cl, xbuf, vbuf, nh, nl, nullptr);
        unsigned short* s; s = ch; ch = nh; nh = s; s = cl; cl = nl; nl = s;
    }
    // iter 30: x30 = x29 + W*Delta_29, written transposed to d_out
    admm_delta<0, 1><<<ig, 256, 0, stream>>>(Whg, Wlg, ch, cl, xbuf, vbuf, nullptr, nullptr, outp);
}

// Round 11
// 1005.921 us; speedup vs baseline: 1.4213x; 1.4213x over previous
//
#include <hip/hip_runtime.h>

// Problem constants (from reference setup_inputs)
#define NVOX   4096   // B voxels
#define NMEAS  256    // M measurements
#define NATOMS 512    // K atoms
#define NITER  30

typedef __attribute__((ext_vector_type(8))) short s8v;   // 8 bf16 (4 VGPR) MFMA frag
typedef __attribute__((ext_vector_type(4))) short s4v;
typedef __attribute__((ext_vector_type(4))) float f32x4;

// bf16 round-to-nearest-even split helpers (no NaN/Inf in this problem)
__device__ __forceinline__ unsigned short f2bf(float x) {
    unsigned u = __builtin_bit_cast(unsigned, x);
    u += 0x7fff + ((u >> 16) & 1);
    return (unsigned short)(u >> 16);
}
__device__ __forceinline__ float bf2f(unsigned short b) {
    unsigned u = ((unsigned)b) << 16;
    return __builtin_bit_cast(float, u);
}
// g(v) = (z - u) collapsed through v = x + u :  relu(v-0.1) - min(v,0.1)
__device__ __forceinline__ float g_of(float v) {
    return fmaxf(v - 0.1f, 0.0f) - fminf(v, 0.1f);
}

// ---------------------------------------------------------------------------
// K0: G = I + A*A^T in fp64 (Gd) + fp32 copy (Gf) for the sweep
// ---------------------------------------------------------------------------
__global__ __launch_bounds__(256) void g_kernel_d(const float* __restrict__ A,
                                                  double* __restrict__ Gd,
                                                  float* __restrict__ Gf) {
    __shared__ float arow[NATOMS];
    int i = blockIdx.x;
    for (int k = threadIdx.x; k < NATOMS; k += 256) arow[k] = A[i * NATOMS + k];
    __syncthreads();
    int j = threadIdx.x;
    const float* aj = A + j * NATOMS;
    double s = (i == j) ? 1.0 : 0.0;
#pragma unroll 4
    for (int k = 0; k < NATOMS; ++k) s += (double)arow[k] * (double)aj[k];
    Gd[i * NMEAS + j] = s;
    Gf[i * NMEAS + j] = (float)s;
}

// ---------------------------------------------------------------------------
// K1: SPD inverse of Gf (256x256) via scalar symmetric SWEEP (r5-proven,
// 255-283us, PASSED). r6-r9 lesson: the register allocator pins 1024/512-thr
// kernels at 64/128 VGPR regardless of hints, spilling blocked-panel working
// sets — scalar form is the accepted local minimum.
// sweep(all pivots) = -G^{-1}; negate on store.
// ---------------------------------------------------------------------------
__global__ __launch_bounds__(1024) void sweep_inverse(const float* __restrict__ src,
                                                      float* __restrict__ dst) {
    __shared__ float s_dn[NMEAS];   // pivot column, row-indexed (uniform reads)
    __shared__ float s_dt[NMEAS];   // strided layout (conflict-free per-lane reads)
    int t = threadIdx.x;
    int rb = t & 31;
    int cb = t >> 5;
    float vals[8][8];
#pragma unroll
    for (int i = 0; i < 8; ++i) {
        const float* row = &src[(8 * rb + i) * NMEAS + 8 * cb];
        float4 a = *(const float4*)row;
        float4 b = *(const float4*)(row + 4);
        vals[i][0] = a.x; vals[i][1] = a.y; vals[i][2] = a.z; vals[i][3] = a.w;
        vals[i][4] = b.x; vals[i][5] = b.y; vals[i][6] = b.z; vals[i][7] = b.w;
    }
#pragma unroll 1
    for (int p = 0; p < NMEAS; ++p) {
        int pb = p >> 3, pi = p & 7;
        __syncthreads();
        if (cb == pb) {
#pragma unroll
            for (int i = 0; i < 8; ++i) {
                float v = vals[i][0];
#pragma unroll
                for (int j = 1; j < 8; ++j) if (pi == j) v = vals[i][j];
                s_dn[8 * rb + i] = v;
                s_dt[i * 32 + rb] = v;
            }
        }
        __syncthreads();
        float d   = s_dn[p];
        float inv = 1.0f / d;
        float rv[8], cv[8];
#pragma unroll
        for (int i = 0; i < 8; ++i) rv[i] = s_dt[i * 32 + rb];
#pragma unroll
        for (int j = 0; j < 8; ++j) cv[j] = s_dn[8 * cb + j] * inv;
#pragma unroll
        for (int i = 0; i < 8; ++i)
#pragma unroll
            for (int j = 0; j < 8; ++j) vals[i][j] -= rv[i] * cv[j];
        if (rb == pb) {
#pragma unroll
            for (int i = 0; i < 8; ++i) if (pi == i) {
#pragma unroll
                for (int j = 0; j < 8; ++j) vals[i][j] = cv[j];
            }
        }
        if (cb == pb) {
#pragma unroll
            for (int j = 0; j < 8; ++j) if (pi == j) {
#pragma unroll
                for (int i = 0; i < 8; ++i)
                    vals[i][j] = (rb == pb && pi == i) ? -inv : rv[i] * inv;
            }
        }
    }
#pragma unroll
    for (int i = 0; i < 8; ++i)
#pragma unroll
        for (int j = 0; j < 8; ++j)
            dst[(8 * rb + i) * NMEAS + 8 * cb + j] = -vals[i][j];
}

// ---------------------------------------------------------------------------
// fp64 Newton refinement:  P = Gd @ X ;  Xn = 2X - X @ P   (X input fp32/fp64)
// (fp32 Newton was the r3/r4 bug: cancellation noise ~cond(G)*eps32)
// ---------------------------------------------------------------------------
template <typename TB>
__global__ __launch_bounds__(256) void mm_gd(const double* __restrict__ Gd,
                                             const TB* __restrict__ X,
                                             double* __restrict__ P) {
    __shared__ __align__(16) double row[NMEAS];
    int i = blockIdx.x;
    row[threadIdx.x] = Gd[i * NMEAS + threadIdx.x];
    __syncthreads();
    int j = threadIdx.x;
    double s = 0.0;
#pragma unroll 4
    for (int k = 0; k < NMEAS; ++k) s += row[k] * (double)X[k * NMEAS + j];
    P[i * NMEAS + j] = s;
}

template <typename TB>
__global__ __launch_bounds__(256) void upd_newton(const TB* __restrict__ X,
                                                  const double* __restrict__ P,
                                                  double* __restrict__ Xn) {
    __shared__ __align__(16) double row[NMEAS];
    int i = blockIdx.x;
    row[threadIdx.x] = (double)X[i * NMEAS + threadIdx.x];
    __syncthreads();
    int j = threadIdx.x;
    double s = 0.0;
#pragma unroll 4
    for (int k = 0; k < NMEAS; ++k) s += row[k] * P[k * NMEAS + j];
    Xn[i * NMEAS + j] = 2.0 * row[j] - s;
}

// ---------------------------------------------------------------------------
// K2: Hd = X2d @ A   (fp64 [256][256] @ fp32 [256][512] -> fp64 [256][512])
// ---------------------------------------------------------------------------
__global__ __launch_bounds__(256) void h_kernel_d(const double* __restrict__ Gi,
                                                  const float* __restrict__ A,
                                                  double* __restrict__ H) {
    __shared__ __align__(16) double grow[NMEAS];
    int i = blockIdx.x;
    grow[threadIdx.x] = Gi[i * NMEAS + threadIdx.x];
    __syncthreads();
    int k0 = threadIdx.x;
    double s0 = 0.0, s1 = 0.0;
#pragma unroll 4
    for (int j = 0; j < NMEAS; ++j) {
        double g = grow[j];
        s0 += g * (double)A[j * NATOMS + k0];
        s1 += g * (double)A[j * NATOMS + k0 + 256];
    }
    H[i * NATOMS + k0] = s0;
    H[i * NATOMS + k0 + 256] = s1;
}

// ---------------------------------------------------------------------------
// K3: W = I - A^T @ Hd  (fp64 accumulate), stored as bf16 hi/lo split
// ---------------------------------------------------------------------------
__global__ __launch_bounds__(256) void w_kernel_d(const float* __restrict__ A,
                                                  const double* __restrict__ H,
                                                  unsigned short* __restrict__ Whg,
                                                  unsigned short* __restrict__ Wlg) {
    __shared__ __align__(16) double acol[NMEAS];
    int p = blockIdx.x;
    acol[threadIdx.x] = (double)A[threadIdx.x * NATOMS + p];
    __syncthreads();
    int q0 = threadIdx.x;
    double s0 = 0.0, s1 = 0.0;
#pragma unroll 4
    for (int m = 0; m < NMEAS; ++m) {
        double a = acol[m];
        s0 += a * H[m * NATOMS + q0];
        s1 += a * H[m * NATOMS + q0 + 256];
    }
    double w0 = ((p == q0)       ? 1.0 : 0.0) - s0;
    double w1 = ((p == q0 + 256) ? 1.0 : 0.0) - s1;
    unsigned short h0 = f2bf((float)w0), h1 = f2bf((float)w1);
    Whg[p * NATOMS + q0]       = h0;
    Wlg[p * NATOMS + q0]       = f2bf((float)(w0 - (double)bf2f(h0)));
    Whg[p * NATOMS + q0 + 256] = h1;
    Wlg[p * NATOMS + q0 + 256] = f2bf((float)(w1 - (double)bf2f(h1)));
}

// ---------------------------------------------------------------------------
// K4: Delta0 = AtY (= t_1, since t_0 = 0), stored split bf16 hi/lo,
//     TRANSPOSED to [4096 voxels][512 atoms] for k-contiguous staging.
// AtY[k][b] = sum_m A[m][k] * Y[b][m]
// ---------------------------------------------------------------------------
__global__ __launch_bounds__(256) void aty_kernel(const float* __restrict__ A,
                                                  const float* __restrict__ Y,
                                                  unsigned short* __restrict__ Dh0,
                                                  unsigned short* __restrict__ Dl0) {
    __shared__ __align__(16) float At[64][65];
    __shared__ __align__(16) float Yt[64][65];
    int b0 = blockIdx.x * 64, k0 = blockIdx.y * 64;
    int t = threadIdx.x, tx = t & 15, ty = t >> 4;
    float acc[4][4] = {};
    for (int m0 = 0; m0 < NMEAS; m0 += 64) {
        __syncthreads();
        {
            int kk = t & 63, mr = t >> 6;
#pragma unroll
            for (int p = 0; p < 16; ++p)
                At[mr + 4 * p][kk] = A[(m0 + mr + 4 * p) * NATOMS + k0 + kk];
            int mm = t & 63, br = t >> 6;
#pragma unroll
            for (int p = 0; p < 16; ++p)
                Yt[mm][br + 4 * p] = Y[(b0 + br + 4 * p) * NMEAS + m0 + mm];
        }
        __syncthreads();
#pragma unroll 4
        for (int m = 0; m < 64; ++m) {
            float av[4], yv[4];
#pragma unroll
            for (int i = 0; i < 4; ++i) av[i] = At[m][ty * 4 + i];
#pragma unroll
            for (int j = 0; j < 4; ++j) yv[j] = Yt[m][tx * 4 + j];
#pragma unroll
            for (int i = 0; i < 4; ++i)
#pragma unroll
                for (int j = 0; j < 4; ++j) acc[i][j] += av[i] * yv[j];
        }
    }
#pragma unroll
    for (int j = 0; j < 4; ++j) {
        int b = b0 + tx * 4 + j;
        s4v h4, l4;
#pragma unroll
        for (int i = 0; i < 4; ++i) {
            float f = acc[i][j];
            unsigned short h = f2bf(f);
            h4[i] = (short)h;
            l4[i] = (short)f2bf(f - bf2f(h));
        }
        *(s4v*)&Dh0[(long)b * NATOMS + k0 + ty * 4] = h4;
        *(s4v*)&Dl0[(long)b * NATOMS + k0 + ty * 4] = l4;
    }
}

// ---------------------------------------------------------------------------
// K5: one ADMM iteration, DELTA form, bf16-split MFMA, 3 terms
//   (Wh*Dh + Wh*Dl + Wl*Dh; dropped Wl*Dl <= 2^-18 rel):
//   dx = W @ Delta_in ; x_k = x_{k-1}+dx ; v_k = x_k + min(v_{k-1},0.1)
//   Delta_out = g(v_k)-g(v_{k-1}) -> split bf16 transposed [n][k]
// LAST: out[b][k] = x_{k-1} + dx  (transposed fp32 write)
// BM=64 x BN=32, BK=32, 256 thr (4 waves), grid 1024 = 4 blocks/CU, 30KB LDS.
// r10 crash fix: BM=64xBN=32 = 4 m-tiles x 2 n-tiles = 8 fragments; wave wv
// owns m-tile wv x n-tiles {0,1} (acc[2]). r10 wrongly gave each wave
// m-tiles {2wv,2wv+1} x n {0,1} (16 fragments) -> m up to 575 -> OOB write
// past d_out -> page fault. Per-C-element K/term order == r9 (bit-identical).
// ---------------------------------------------------------------------------
template <int FIRST, int LAST>
__global__ __launch_bounds__(256) void admm_delta(
        const unsigned short* __restrict__ Whg,
        const unsigned short* __restrict__ Wlg,
        const unsigned short* __restrict__ Dhg,
        const unsigned short* __restrict__ Dlg,
        float* __restrict__ xbuf,            // fp32 x [512][4096], in-place
        float* __restrict__ vbuf,            // fp32 v [512][4096], in-place (d_out)
        unsigned short* __restrict__ DhOut,
        unsigned short* __restrict__ DlOut,
        float* __restrict__ out) {
    __shared__ __align__(16) char smem[30720];
    unsigned short* Whs = (unsigned short*)smem;      // [2][64*40]
    unsigned short* Wls = Whs + 2 * 64 * 40;          // [2][64*40]
    unsigned short* Dhs = Wls + 2 * 64 * 40;          // [2][32*40]
    unsigned short* Dls = Dhs + 2 * 32 * 40;          // [2][32*40]

    const int t = threadIdx.x;
    const int lane = t & 63, wv = t >> 6;
    const int ln = lane & 15, kg = lane >> 4;

    // XCD-aware bijective swizzle (grid 1024 = 128x8, 8 XCDs, 128 blocks ea):
    // XCD k gets bx in [16k,16k+16) x all by -> per-XCD L2: W 1MB + D ~1MB.
    int bid = blockIdx.x + (blockIdx.y << 7);
    int xr = bid & 7, q = bid >> 3;
    int bx = xr * 16 + (q >> 3);         // [0,128)
    int by = q & 7;                      // [0,8)
    const int n0 = bx * 32, m0 = by * 64;

    const int wm = t >> 2, wslot = t & 3;          // W staging: 64 rows x 4 slots
    const int dn = (t & 127) >> 2, dslot = t & 3;  // D staging: 32 rows x 4 slots
    const unsigned short* Dg  = (t < 128) ? Dhg : Dlg;  // wave-uniform select
    unsigned short*       Dsb = (t < 128) ? Dhs : Dls;

    f32x4 acc[2] = {};
    s8v rwh, rwl, rd;

#define GLOAD(kc)                                                             \
    {                                                                         \
        long ko = (long)(kc)*32;                                              \
        rwh = *(const s8v*)&Whg[(long)(m0 + wm) * NATOMS + ko + wslot * 8];   \
        rwl = *(const s8v*)&Wlg[(long)(m0 + wm) * NATOMS + ko + wslot * 8];   \
        rd  = *(const s8v*)&Dg [(long)(n0 + dn) * NATOMS + ko + dslot * 8];   \
    }
#define DSWRITE(b)                                                  \
    {                                                               \
        *(s8v*)&Whs[(b)*2560 + wm * 40 + wslot * 8] = rwh;          \
        *(s8v*)&Wls[(b)*2560 + wm * 40 + wslot * 8] = rwl;          \
        *(s8v*)&Dsb[(b)*1280 + dn * 40 + dslot * 8] = rd;           \
    }

    GLOAD(0);
    DSWRITE(0);
#pragma unroll 1
    for (int c = 0; c < 16; ++c) {
        if (c < 15) GLOAD(c + 1);          // issue next chunk's loads early
        __syncthreads();                    // current buffer's ds_writes visible
        const int b = c & 1;
        const unsigned short* wh = &Whs[b * 2560];
        const unsigned short* wl = &Wls[b * 2560];
        const unsigned short* dh = &Dhs[b * 1280];
        const unsigned short* dl = &Dls[b * 1280];
        s8v ah, al, bh[2], bl[2];
        {
            int row = wv * 16 + ln;        // wave wv owns m-tile wv
            ah = *(const s8v*)&wh[row * 40 + kg * 8];
            al = *(const s8v*)&wl[row * 40 + kg * 8];
        }
#pragma unroll
        for (int ni = 0; ni < 2; ++ni) {
            int row = ni * 16 + ln;
            bh[ni] = *(const s8v*)&dh[row * 40 + kg * 8];
            bl[ni] = *(const s8v*)&dl[row * 40 + kg * 8];
        }
#pragma unroll
        for (int ni = 0; ni < 2; ++ni) {
            acc[ni] = __builtin_amdgcn_mfma_f32_16x16x32_bf16(ah, bh[ni], acc[ni], 0, 0, 0);
            acc[ni] = __builtin_amdgcn_mfma_f32_16x16x32_bf16(ah, bl[ni], acc[ni], 0, 0, 0);
            acc[ni] = __builtin_amdgcn_mfma_f32_16x16x32_bf16(al, bh[ni], acc[ni], 0, 0, 0);
        }
        if (c < 15) DSWRITE((c + 1) & 1);  // prev use of that buffer done pre-barrier
    }
#undef GLOAD
#undef DSWRITE

    __syncthreads();                        // staging LDS dead; reuse as xT [32][68] f32
    float* xT = (float*)smem;

    if (!LAST) {
#pragma unroll
        for (int ni = 0; ni < 2; ++ni) {
            int nn = n0 + ni * 16 + ln;
            f32x4 dlt;
#pragma unroll
            for (int j = 0; j < 4; ++j) {
                int m = m0 + wv * 16 + kg * 4 + j;
                long idx = (long)m * NVOX + nn;
                float dx = acc[ni][j];
                float xn, vn, gold;
                if (FIRST) {
                    xn = dx; vn = xn; gold = 0.0f;   // x0=0, u0=0, v0=0
                } else {
                    xn = xbuf[idx] + dx;
                    float vp = vbuf[idx];
                    vn = xn + fminf(vp, 0.1f);
                    gold = g_of(vp);
                }
                xbuf[idx] = xn;
                vbuf[idx] = vn;
                dlt[j] = g_of(vn) - gold;
            }
            int nl = ni * 16 + ln;
            int ml = wv * 16 + kg * 4;
            *(f32x4*)&xT[nl * 68 + ml] = dlt;
        }
        __syncthreads();
        int nl = t >> 3, seg = t & 7;        // 32 rows x 8 m-cols per thread
        {
            s8v hv, lv;
#pragma unroll
            for (int e = 0; e < 8; ++e) {
                float f = xT[nl * 68 + seg * 8 + e];
                unsigned short h = f2bf(f);
                hv[e] = (short)h;
                lv[e] = (short)f2bf(f - bf2f(h));
            }
            *(s8v*)&DhOut[(long)(n0 + nl) * NATOMS + m0 + seg * 8] = hv;
            *(s8v*)&DlOut[(long)(n0 + nl) * NATOMS + m0 + seg * 8] = lv;
        }
    } else {
        // LAST: out[b][k] = x_{k-1}[k][b] + dx  (transposed fp32 write)
#pragma unroll
        for (int ni = 0; ni < 2; ++ni) {
            int nn = n0 + ni * 16 + ln;
            f32x4 tv;
#pragma unroll
            for (int j = 0; j < 4; ++j) {
                int m = m0 + wv * 16 + kg * 4 + j;
                tv[j] = xbuf[(long)m * NVOX + nn] + acc[ni][j];
            }
            int nl = ni * 16 + ln;
            int ml = wv * 16 + kg * 4;
            *(f32x4*)&xT[nl * 68 + ml] = tv;
        }
        __syncthreads();
        int nl = t >> 3, seg = t & 7;
#pragma unroll
        for (int qq = 0; qq < 2; ++qq) {
            f32x4 v = *(const f32x4*)&xT[nl * 68 + seg * 8 + qq * 4];
            *(f32x4*)&out[(long)(n0 + nl) * NATOMS + m0 + seg * 8 + qq * 4] = v;
        }
    }
}

// ---------------------------------------------------------------------------
extern "C" void kernel_launch(void* const* d_in, const int* in_sizes, int n_in,
                              void* d_out, int out_size, void* d_ws, size_t ws_size,
                              hipStream_t stream) {
    const float* Y = (const float*)d_in[0];   // [4096][256]
    const float* A = (const float*)d_in[1];   // [256][512]

    // ws layout (float units), lifetime-checked overlays; total 6946816 floats
    // = 26.5 MiB (r3-r9 proven footprint).
    float* ws = (float*)d_ws;
    double* Gd  = (double*)(ws + 0);        // [0,131072)       dead after step 5
    float*  Gf  = ws + 131072;              // [131072,196608)  dead after sweep
    float*  X0f = ws + 196608;              // [196608,262144)  dead after step 4
    double* X1d = (double*)(ws + 262144);   // [262144,393216)  dead after step 6
    double* Pd  = (double*)(ws + 393216);   // [393216,524288)  dead after step 6
    double* X2d = (double*)(ws + 131072);   // overlays Gf+X0f (both dead)
    double* Hd  = (double*)(ws + 393216);   // [393216,655360) overlays Pd (dead)
    float*  xbuf = ws + 655360;             // [655360,2752512) fp32 x state
    unsigned short* Whg = (unsigned short*)(ws + 0);        // overlays Gd (dead)
    unsigned short* Wlg = (unsigned short*)(ws + 131072);   // overlays X2d (dead after h)
    unsigned short* DAh = (unsigned short*)(ws + 2752512);
    unsigned short* DAl = (unsigned short*)(ws + 3801088);
    unsigned short* DBh = (unsigned short*)(ws + 4849664);
    unsigned short* DBl = (unsigned short*)(ws + 5898240);  // end 6946816
    float* vbuf = (float*)d_out;   // v_k fp32, iters 1..29 (d_out as scratch)
    float* outp = (float*)d_out;   // final output, written by LAST iter only

    g_kernel_d<<<256, 256, 0, stream>>>(A, Gd, Gf);                 // 1
    sweep_inverse<<<1, 1024, 0, stream>>>(Gf, X0f);                 // 2
    mm_gd<float><<<256, 256, 0, stream>>>(Gd, X0f, Pd);             // 3
    upd_newton<float><<<256, 256, 0, stream>>>(X0f, Pd, X1d);       // 4
    mm_gd<double><<<256, 256, 0, stream>>>(Gd, X1d, Pd);            // 5
    upd_newton<double><<<256, 256, 0, stream>>>(X1d, Pd, X2d);      // 6
    h_kernel_d<<<256, 256, 0, stream>>>(X2d, A, Hd);                // 7
    w_kernel_d<<<512, 256, 0, stream>>>(A, Hd, Whg, Wlg);           // 8
    aty_kernel<<<dim3(64, 8), 256, 0, stream>>>(A, Y, DAh, DAl);    // 9

    dim3 ig(NVOX / 32, NATOMS / 64);  // (128, 8) = 1024 blocks = 4/CU
    unsigned short *ch = DAh, *cl = DAl, *nh = DBh, *nl = DBl;
    // iter 1: Delta_0 = AtY; x1 = W*AtY; v1 = x1; Delta_1 = g(v1)
    admm_delta<1, 0><<<ig, 256, 0, stream>>>(Whg, Wlg, ch, cl, xbuf, vbuf, nh, nl, nullptr);
    { unsigned short* s; s = ch; ch = nh; nh = s; s = cl; cl = nl; nl = s; }
    for (int it = 2; it <= NITER - 1; ++it) {
        admm_delta<0, 0><<<ig, 256, 0, stream>>>(Whg, Wlg, ch, cl, xbuf, vbuf, nh, nl, nullptr);
        unsigned short* s; s = ch; ch = nh; nh = s; s = cl; cl = nl; nl = s;
    }
    // iter 30: x30 = x29 + W*Delta_29, written transposed to d_out
    admm_delta<0, 1><<<ig, 256, 0, stream>>>(Whg, Wlg, ch, cl, xbuf, vbuf, nullptr, nullptr, outp);
}